// Round 3
// baseline (1731.199 us; speedup 1.0000x reference)
//
#include <hip/hip_runtime.h>
#include <hip/hip_fp16.h>

#define TT 64
#define BB 64
#define EE 128
#define HH 256
#define VV 32000

typedef _Float16 f16;
typedef _Float16 f16x2 __attribute__((ext_vector_type(2)));
typedef _Float16 f16x8 __attribute__((ext_vector_type(8)));
typedef float f32x4 __attribute__((ext_vector_type(4)));
typedef unsigned u32x4 __attribute__((ext_vector_type(4)));

#if __has_builtin(__builtin_amdgcn_fdot2)
__device__ __forceinline__ float fdot2u(unsigned a, unsigned b, float c) {
    return __builtin_amdgcn_fdot2(__builtin_bit_cast(f16x2, a),
                                  __builtin_bit_cast(f16x2, b), c, false);
}
#else
__device__ __forceinline__ float fdot2u(unsigned a, unsigned b, float c) {
    f16x2 av = __builtin_bit_cast(f16x2, a), bv = __builtin_bit_cast(f16x2, b);
    return c + (float)av[0] * (float)bv[0] + (float)av[1] * (float)bv[1];
}
#endif

__device__ __forceinline__ float sigmoid_f(float x) {
    return 1.f / (1.f + __expf(-x));
}
__device__ __forceinline__ float tanh_f(float x) {
    float e = __expf(2.f * x);
    return 1.f - 2.f / (e + 1.f);   // saturates correctly for |x| large
}

// ---- prep: pack U gates as f16 octets:
// Upk8[((g*32 + ko)*256 + u)] (f16x8 units) = U_g[8ko+j][u], j=0..7
__global__ void k_prep_u(const float* __restrict__ Ui, const float* __restrict__ Uf,
                         const float* __restrict__ Uog, const float* __restrict__ Uc,
                         f16* __restrict__ Upk8) {
    int idx = blockIdx.x * 256 + threadIdx.x;          // 4*32*256 = 32768
    if (idx >= 4 * 32 * 256) return;
    int u = idx & 255, ko = (idx >> 8) & 31, g = idx >> 13;
    const float* Ug = (g == 0) ? Ui : (g == 1) ? Uf : (g == 2) ? Uog : Uc;
    f16x8 v;
    #pragma unroll
    for (int j = 0; j < 8; ++j) v[j] = (f16)Ug[(8 * ko + j) * HH + u];
    ((f16x8*)Upk8)[idx] = v;
}

// ---- prep: WoT[v][k] = (f16) Wo[k][v]   (transpose for contiguous-k MFMA B frags)
__global__ void k_prep_wot(const float* __restrict__ Wo, unsigned short* __restrict__ WoT) {
    __shared__ unsigned short lds[64][258];            // pad -> conflict-free
    int v0 = blockIdx.x * 64;
    int tid = threadIdx.x;
    int vl = tid & 63, kq = tid >> 6;
    for (int it = 0; it < 64; ++it) {
        int k = it * 4 + kq;
        float w = Wo[(size_t)k * VV + v0 + vl];
        lds[vl][k] = __builtin_bit_cast(unsigned short, (f16)w);
    }
    __syncthreads();
    for (int r = 0; r < 64; ++r)
        WoT[(size_t)(v0 + r) * HH + tid] = lds[r][tid];
}

__global__ void k_zero(float* __restrict__ p, int n) {
    int i = blockIdx.x * 256 + threadIdx.x;
    if (i < n) p[i] = 0.f;
}

// ---- Gx[(t*64+b)*1024 + g*256 + u]; 8 rows per block for W reuse
__global__ __launch_bounds__(256) void k_gx(const int* __restrict__ x, const float* __restrict__ emb,
                     const float* __restrict__ Wi, const float* __restrict__ Wf,
                     const float* __restrict__ Wog, const float* __restrict__ Wc,
                     const float* __restrict__ bi, const float* __restrict__ bfv,
                     const float* __restrict__ bog, const float* __restrict__ bc,
                     float* __restrict__ Gx) {
    __shared__ float xs[8][EE];
    int base = blockIdx.x * 8;           // grid 512
    int tid = threadIdx.x;               // = hidden unit u
    for (int i = tid; i < 8 * EE; i += 256) {
        int r = i >> 7, k = i & 127;
        int bx = base + r, t = bx >> 6, b = bx & 63;
        int tok = (t == 0) ? 0 : x[b * TT + (t - 1)];
        xs[r][k] = emb[(size_t)tok * EE + k];
    }
    __syncthreads();
    float acc[4][8];
    float b0 = bi[tid], b1 = bfv[tid], b2 = bog[tid], b3 = bc[tid];
    #pragma unroll
    for (int r = 0; r < 8; ++r) {
        acc[0][r] = b0; acc[1][r] = b1; acc[2][r] = b2; acc[3][r] = b3;
    }
    for (int k = 0; k < EE; ++k) {
        float w0 = Wi[k * HH + tid], w1 = Wf[k * HH + tid];
        float w2 = Wog[k * HH + tid], w3 = Wc[k * HH + tid];
        #pragma unroll
        for (int r = 0; r < 8; ++r) {
            float xv = xs[r][k];
            acc[0][r] = fmaf(xv, w0, acc[0][r]);
            acc[1][r] = fmaf(xv, w1, acc[1][r]);
            acc[2][r] = fmaf(xv, w2, acc[2][r]);
            acc[3][r] = fmaf(xv, w3, acc[3][r]);
        }
    }
    #pragma unroll
    for (int r = 0; r < 8; ++r) {
        float* o = Gx + (size_t)(base + r) * 1024;
        o[tid] = acc[0][r]; o[256 + tid] = acc[1][r];
        o[512 + tid] = acc[2][r]; o[768 + tid] = acc[3][r];
    }
}

// ---- recurrence: one block per batch element, U fully CU-resident.
// 512 thr: u = tid&255, half = tid>>8 (K-split).
// LDS: U_c (128KB, [k2][u] u32 pairs) + part (4KB) + h16 (512B) = 135.7KB.
// Regs: U_i/U_f/U_o K-half columns = u32x4 Ur[3][16] = 192 VGPRs, static-indexed.
__global__ __launch_bounds__(512) void k_lstm(const float* __restrict__ Gx,
                                              const f16* __restrict__ Upk8,
                                              unsigned short* __restrict__ Hall) {
    __shared__ unsigned Uc[128 * 256];                 // 128 KB
    __shared__ float part[4][256];                     // half=1 partials
    __shared__ __align__(16) unsigned short h16[HH];   // h state, f16
    int b = blockIdx.x, tid = threadIdx.x;
    int u = tid & 255, half = tid >> 8;
    const u32x4* U4 = (const u32x4*)Upk8;

    // fill U_c into LDS: gate 3 of Upk8; word (4ko+j2)*256+u = f16 pair (k=8ko+2j2, +1)
    for (int idx = tid; idx < 32 * 256; idx += 512) {
        int ko = idx >> 8, uu = idx & 255;
        u32x4 q = U4[(96 + ko) * 256 + uu];
        int k2b = 4 * ko;
        Uc[(k2b + 0) * 256 + uu] = q.x;
        Uc[(k2b + 1) * 256 + uu] = q.y;
        Uc[(k2b + 2) * 256 + uu] = q.z;
        Uc[(k2b + 3) * 256 + uu] = q.w;
    }
    if (tid < HH / 2) ((unsigned*)h16)[tid] = 0u;

    // register-resident U for gates i,f,o: this thread's (u, K-half) columns
    u32x4 Ur[3][16];
    #pragma unroll
    for (int g = 0; g < 3; ++g) {
        #pragma unroll
        for (int i = 0; i < 16; ++i)
            Ur[g][i] = U4[(size_t)((g * 32 + half * 16 + i) * 256 + u)];
    }
    float c = 0.f;
    __syncthreads();

    int kb2 = half * 64;                               // h-word base for this half
    const unsigned* hw = (const unsigned*)h16;
    for (int t = 0; t < TT; ++t) {
        float acc0, acc1, acc2, acc3;
        if (half == 0) {
            const float* gx = Gx + ((size_t)t * BB + b) * 1024;
            acc0 = gx[u]; acc1 = gx[256 + u]; acc2 = gx[512 + u]; acc3 = gx[768 + u];
        } else {
            acc0 = acc1 = acc2 = acc3 = 0.f;
        }
        #pragma unroll
        for (int i = 0; i < 16; ++i) {
            u32x4 hv = *(const u32x4*)(hw + kb2 + 4 * i);      // broadcast, free
            unsigned cw0 = Uc[(kb2 + 4 * i + 0) * 256 + u];    // 2-way bank alias, free
            unsigned cw1 = Uc[(kb2 + 4 * i + 1) * 256 + u];
            unsigned cw2 = Uc[(kb2 + 4 * i + 2) * 256 + u];
            unsigned cw3 = Uc[(kb2 + 4 * i + 3) * 256 + u];
            acc0 = fdot2u(hv.x, Ur[0][i].x, acc0); acc0 = fdot2u(hv.y, Ur[0][i].y, acc0);
            acc0 = fdot2u(hv.z, Ur[0][i].z, acc0); acc0 = fdot2u(hv.w, Ur[0][i].w, acc0);
            acc1 = fdot2u(hv.x, Ur[1][i].x, acc1); acc1 = fdot2u(hv.y, Ur[1][i].y, acc1);
            acc1 = fdot2u(hv.z, Ur[1][i].z, acc1); acc1 = fdot2u(hv.w, Ur[1][i].w, acc1);
            acc2 = fdot2u(hv.x, Ur[2][i].x, acc2); acc2 = fdot2u(hv.y, Ur[2][i].y, acc2);
            acc2 = fdot2u(hv.z, Ur[2][i].z, acc2); acc2 = fdot2u(hv.w, Ur[2][i].w, acc2);
            acc3 = fdot2u(hv.x, cw0, acc3); acc3 = fdot2u(hv.y, cw1, acc3);
            acc3 = fdot2u(hv.z, cw2, acc3); acc3 = fdot2u(hv.w, cw3, acc3);
        }
        if (half == 1) {
            part[0][u] = acc0; part[1][u] = acc1; part[2][u] = acc2; part[3][u] = acc3;
        }
        __syncthreads();
        if (half == 0) {
            float p0 = acc0 + part[0][u];
            float p1 = acc1 + part[1][u];
            float p2 = acc2 + part[2][u];
            float p3 = acc3 + part[3][u];
            float ig = sigmoid_f(p0), fg = sigmoid_f(p1), og = sigmoid_f(p2);
            float ch = tanh_f(p3);
            c = fg * c + ig * ch;
            float hn = og * tanh_f(c);
            unsigned short hbits = __builtin_bit_cast(unsigned short, (f16)hn);
            h16[u] = hbits;
            Hall[((size_t)b * TT + t) * HH + u] = hbits;   // row r = b*64 + t
        }
        __syncthreads();
    }
}

// ---- pass 1: logits -> exp -> per-row sums (atomicAdd). No 524MB store.
// grid: 640 = 64 m-tiles (fast) x 10 n-slices. block 512 thr = 8 waves (4M x 2N).
__global__ __launch_bounds__(512) void k_rowsum(const unsigned short* __restrict__ Hall,
                                                const unsigned short* __restrict__ WoT,
                                                const float* __restrict__ bo,
                                                float* __restrict__ rowsum) {
    int bx = blockIdx.x;
    int mt = bx & 63, nt = bx >> 6;
    int tid = threadIdx.x, w = tid >> 6, lane = tid & 63;
    int wm = w & 3, wn = w >> 2;
    int r0 = mt * 64 + wm * 16;
    int c0 = nt * 3200 + wn * 1600;
    int lrow = lane & 15, lk = (lane >> 4) * 8;
    f16x8 a[8];
    const unsigned short* arow = Hall + (size_t)(r0 + lrow) * HH + lk;
    #pragma unroll
    for (int kf = 0; kf < 8; ++kf) a[kf] = *(const f16x8*)(arow + kf * 32);
    float rs0 = 0.f, rs1 = 0.f, rs2 = 0.f, rs3 = 0.f;
    for (int nf = 0; nf < 100; ++nf) {
        int v = c0 + nf * 16 + lrow;
        const unsigned short* brow = WoT + (size_t)v * HH + lk;
        f32x4 acc = {0.f, 0.f, 0.f, 0.f};
        #pragma unroll
        for (int kf = 0; kf < 8; ++kf) {
            f16x8 bfr = *(const f16x8*)(brow + kf * 32);
            acc = __builtin_amdgcn_mfma_f32_16x16x32_f16(a[kf], bfr, acc, 0, 0, 0);
        }
        float bv = bo[v];
        rs0 += __expf(fminf(acc[0] + bv, 60.f));
        rs1 += __expf(fminf(acc[1] + bv, 60.f));
        rs2 += __expf(fminf(acc[2] + bv, 60.f));
        rs3 += __expf(fminf(acc[3] + bv, 60.f));
    }
    #pragma unroll
    for (int off = 1; off < 16; off <<= 1) {
        rs0 += __shfl_xor(rs0, off, 64);
        rs1 += __shfl_xor(rs1, off, 64);
        rs2 += __shfl_xor(rs2, off, 64);
        rs3 += __shfl_xor(rs3, off, 64);
    }
    if ((lane & 15) == 0) {
        int rb = r0 + (lane >> 4) * 4;
        atomicAdd(&rowsum[rb + 0], rs0);
        atomicAdd(&rowsum[rb + 1], rs1);
        atomicAdd(&rowsum[rb + 2], rs2);
        atomicAdd(&rowsum[rb + 3], rs3);
    }
}

// ---- pass 2: recompute logits, write exp(l)/rowsum directly to out[b][t][v] (row r = b*64+t)
__global__ __launch_bounds__(512) void k_out(const unsigned short* __restrict__ Hall,
                                             const unsigned short* __restrict__ WoT,
                                             const float* __restrict__ bo,
                                             const float* __restrict__ rowsum,
                                             float* __restrict__ out) {
    int bx = blockIdx.x;
    int mt = bx & 63, nt = bx >> 6;
    int tid = threadIdx.x, w = tid >> 6, lane = tid & 63;
    int wm = w & 3, wn = w >> 2;
    int r0 = mt * 64 + wm * 16;
    int c0 = nt * 3200 + wn * 1600;
    int lrow = lane & 15, lk = (lane >> 4) * 8;
    f16x8 a[8];
    const unsigned short* arow = Hall + (size_t)(r0 + lrow) * HH + lk;
    #pragma unroll
    for (int kf = 0; kf < 8; ++kf) a[kf] = *(const f16x8*)(arow + kf * 32);
    int rr = r0 + (lane >> 4) * 4;
    float ri0 = 1.f / rowsum[rr + 0];
    float ri1 = 1.f / rowsum[rr + 1];
    float ri2 = 1.f / rowsum[rr + 2];
    float ri3 = 1.f / rowsum[rr + 3];
    float* o0 = out + (size_t)(rr + 0) * VV;
    float* o1 = out + (size_t)(rr + 1) * VV;
    float* o2 = out + (size_t)(rr + 2) * VV;
    float* o3 = out + (size_t)(rr + 3) * VV;
    for (int nf = 0; nf < 100; ++nf) {
        int v = c0 + nf * 16 + lrow;
        const unsigned short* brow = WoT + (size_t)v * HH + lk;
        f32x4 acc = {0.f, 0.f, 0.f, 0.f};
        #pragma unroll
        for (int kf = 0; kf < 8; ++kf) {
            f16x8 bfr = *(const f16x8*)(brow + kf * 32);
            acc = __builtin_amdgcn_mfma_f32_16x16x32_f16(a[kf], bfr, acc, 0, 0, 0);
        }
        float bv = bo[v];
        o0[v] = __expf(fminf(acc[0] + bv, 60.f)) * ri0;
        o1[v] = __expf(fminf(acc[1] + bv, 60.f)) * ri1;
        o2[v] = __expf(fminf(acc[2] + bv, 60.f)) * ri2;
        o3[v] = __expf(fminf(acc[3] + bv, 60.f)) * ri3;
    }
}

extern "C" void kernel_launch(void* const* d_in, const int* in_sizes, int n_in,
                              void* d_out, int out_size, void* d_ws, size_t ws_size,
                              hipStream_t stream) {
    const int*   x    = (const int*)  d_in[0];
    const float* emb  = (const float*)d_in[1];
    const float* Wi   = (const float*)d_in[2];
    const float* Ui   = (const float*)d_in[3];
    const float* bi   = (const float*)d_in[4];
    const float* Wf   = (const float*)d_in[5];
    const float* Uf   = (const float*)d_in[6];
    const float* bfv  = (const float*)d_in[7];
    const float* Wog  = (const float*)d_in[8];
    const float* Uog  = (const float*)d_in[9];
    const float* bog  = (const float*)d_in[10];
    const float* Wc   = (const float*)d_in[11];
    const float* Uc   = (const float*)d_in[12];
    const float* bc   = (const float*)d_in[13];
    const float* Wo   = (const float*)d_in[14];
    const float* bo   = (const float*)d_in[15];
    float* out = (float*)d_out;
    char* ws = (char*)d_ws;

    // ws layout (~18.2 MB): Upk8 512KB | Hall 2MB | WoT 16,384,000B | rowsum 16KB
    f16*            Upk8   = (f16*)(ws);
    unsigned short* Hall   = (unsigned short*)(ws + (512u << 10));
    unsigned short* WoT    = (unsigned short*)(ws + (512u << 10) + (2u << 20));
    float*          rowsum = (float*)(ws + (512u << 10) + (2u << 20) + 16384000u);
    float*          Gx     = out;   // 16 MB scratch inside d_out; dead before k_out writes

    k_prep_u  <<<128, 256, 0, stream>>>(Ui, Uf, Uog, Uc, Upk8);
    k_prep_wot<<<500, 256, 0, stream>>>(Wo, WoT);
    k_zero    <<<16, 256, 0, stream>>>(rowsum, BB * TT);
    k_gx      <<<512, 256, 0, stream>>>(x, emb, Wi, Wf, Wog, Wc, bi, bfv, bog, bc, Gx);
    k_lstm    <<<64, 512, 0, stream>>>(Gx, Upk8, Hall);
    k_rowsum  <<<640, 512, 0, stream>>>(Hall, WoT, bo, rowsum);
    k_out     <<<640, 512, 0, stream>>>(Hall, WoT, bo, rowsum, out);
}

// Round 6
// 938.861 us; speedup vs baseline: 1.8439x; 1.8439x over previous
//
#include <hip/hip_runtime.h>
#include <hip/hip_fp16.h>

#define TT 64
#define BB 64
#define EE 128
#define HH 256
#define VV 32000
#define NT_TILES 25          // col-tiles per block (16 cols each)
#define SLICE 400            // NT_TILES*16
#define GRID_MN 1280         // 16 m-tiles x 80 n-slices = 5*256 (no tail)

typedef _Float16 f16;
typedef _Float16 f16x2 __attribute__((ext_vector_type(2)));
typedef _Float16 f16x8 __attribute__((ext_vector_type(8)));
typedef float f32x4 __attribute__((ext_vector_type(4)));
typedef unsigned u32x4 __attribute__((ext_vector_type(4)));

#if __has_builtin(__builtin_amdgcn_fdot2)
__device__ __forceinline__ float fdot2u(unsigned a, unsigned b, float c) {
    return __builtin_amdgcn_fdot2(__builtin_bit_cast(f16x2, a),
                                  __builtin_bit_cast(f16x2, b), c, false);
}
#else
__device__ __forceinline__ float fdot2u(unsigned a, unsigned b, float c) {
    f16x2 av = __builtin_bit_cast(f16x2, a), bv = __builtin_bit_cast(f16x2, b);
    return c + (float)av[0] * (float)bv[0] + (float)av[1] * (float)bv[1];
}
#endif

__device__ __forceinline__ float sigmoid_f(float x) {
    return 1.f / (1.f + __expf(-x));
}
__device__ __forceinline__ float tanh_f(float x) {
    float e = __expf(2.f * x);
    return 1.f - 2.f / (e + 1.f);   // saturates correctly for |x| large
}

// ---- prep: pack U gates as f16 octets:
// Upk8[((g*32 + ko)*256 + u)] (f16x8 units) = U_g[8ko+j][u], j=0..7
__global__ void k_prep_u(const float* __restrict__ Ui, const float* __restrict__ Uf,
                         const float* __restrict__ Uog, const float* __restrict__ Uc,
                         f16* __restrict__ Upk8) {
    int idx = blockIdx.x * 256 + threadIdx.x;          // 4*32*256 = 32768
    if (idx >= 4 * 32 * 256) return;
    int u = idx & 255, ko = (idx >> 8) & 31, g = idx >> 13;
    const float* Ug = (g == 0) ? Ui : (g == 1) ? Uf : (g == 2) ? Uog : Uc;
    f16x8 v;
    #pragma unroll
    for (int j = 0; j < 8; ++j) v[j] = (f16)Ug[(8 * ko + j) * HH + u];
    ((f16x8*)Upk8)[idx] = v;
}

// ---- prep: WoT[v][k] = (f16) Wo[k][v]   (transpose for contiguous-k MFMA B frags)
__global__ void k_prep_wot(const float* __restrict__ Wo, unsigned short* __restrict__ WoT) {
    __shared__ unsigned short lds[64][258];            // pad -> conflict-free
    int v0 = blockIdx.x * 64;
    int tid = threadIdx.x;
    int vl = tid & 63, kq = tid >> 6;
    for (int it = 0; it < 64; ++it) {
        int k = it * 4 + kq;
        float w = Wo[(size_t)k * VV + v0 + vl];
        lds[vl][k] = __builtin_bit_cast(unsigned short, (f16)w);
    }
    __syncthreads();
    for (int r = 0; r < 64; ++r)
        WoT[(size_t)(v0 + r) * HH + tid] = lds[r][tid];
}

__global__ void k_zero(float* __restrict__ p, int n) {
    int i = blockIdx.x * 256 + threadIdx.x;
    if (i < n) p[i] = 0.f;
}

// ---- Gx[(t*64+b)*1024 + g*256 + u]; 8 rows per block for W reuse
__global__ __launch_bounds__(256) void k_gx(const int* __restrict__ x, const float* __restrict__ emb,
                     const float* __restrict__ Wi, const float* __restrict__ Wf,
                     const float* __restrict__ Wog, const float* __restrict__ Wc,
                     const float* __restrict__ bi, const float* __restrict__ bfv,
                     const float* __restrict__ bog, const float* __restrict__ bc,
                     float* __restrict__ Gx) {
    __shared__ float xs[8][EE];
    int base = blockIdx.x * 8;           // grid 512
    int tid = threadIdx.x;               // = hidden unit u
    for (int i = tid; i < 8 * EE; i += 256) {
        int r = i >> 7, k = i & 127;
        int bx = base + r, t = bx >> 6, b = bx & 63;
        int tok = (t == 0) ? 0 : x[b * TT + (t - 1)];
        xs[r][k] = emb[(size_t)tok * EE + k];
    }
    __syncthreads();
    float acc[4][8];
    float b0 = bi[tid], b1 = bfv[tid], b2 = bog[tid], b3 = bc[tid];
    #pragma unroll
    for (int r = 0; r < 8; ++r) {
        acc[0][r] = b0; acc[1][r] = b1; acc[2][r] = b2; acc[3][r] = b3;
    }
    for (int k = 0; k < EE; ++k) {
        float w0 = Wi[k * HH + tid], w1 = Wf[k * HH + tid];
        float w2 = Wog[k * HH + tid], w3 = Wc[k * HH + tid];
        #pragma unroll
        for (int r = 0; r < 8; ++r) {
            float xv = xs[r][k];
            acc[0][r] = fmaf(xv, w0, acc[0][r]);
            acc[1][r] = fmaf(xv, w1, acc[1][r]);
            acc[2][r] = fmaf(xv, w2, acc[2][r]);
            acc[3][r] = fmaf(xv, w3, acc[3][r]);
        }
    }
    #pragma unroll
    for (int r = 0; r < 8; ++r) {
        float* o = Gx + (size_t)(base + r) * 1024;
        o[tid] = acc[0][r]; o[256 + tid] = acc[1][r];
        o[512 + tid] = acc[2][r]; o[768 + tid] = acc[3][r];
    }
}

// ---- recurrence: one block per batch element, U fully CU-resident.
// 512 thr: u = tid&255, half = tid>>8 (K-split).
// LDS: U_c column-major-per-thread, XOR-swizzled chunks (one b128/inner-iter):
//   byte(u, c) = u*512 + ((c*16) ^ ((u&31)<<4)), c = 0..31 (16B chunk = 4 h-pairs)
// Regs: U_i/U_f/U_o K-half columns = u32x4 Ur[3][16] = 192 VGPRs, static-indexed.
__global__ __launch_bounds__(512) void k_lstm(const float* __restrict__ Gx,
                                              const f16* __restrict__ Upk8,
                                              unsigned short* __restrict__ Hall) {
    __shared__ __align__(16) char UcB[256 * 512];      // 128 KB
    __shared__ float part[4][256];                     // half=1 partials
    __shared__ __align__(16) unsigned short h16[HH];   // h state, f16
    int b = blockIdx.x, tid = threadIdx.x;
    int u = tid & 255, half = tid >> 8;
    const u32x4* U4 = (const u32x4*)Upk8;

    // fill U_c: octet ko of column uu == chunk ko of column uu (pure repack)
    for (int idx = tid; idx < 32 * 256; idx += 512) {
        int ko = idx >> 8, uu = idx & 255;
        u32x4 q = U4[(96 + ko) * 256 + uu];
        *(u32x4*)(UcB + uu * 512 + ((ko * 16) ^ ((uu & 31) << 4))) = q;
    }
    if (tid < HH / 2) ((unsigned*)h16)[tid] = 0u;

    // register-resident U for gates i,f,o: this thread's (u, K-half) columns
    u32x4 Ur[3][16];
    #pragma unroll
    for (int g = 0; g < 3; ++g) {
        #pragma unroll
        for (int i = 0; i < 16; ++i)
            Ur[g][i] = U4[(size_t)((g * 32 + half * 16 + i) * 256 + u)];
    }
    float c = 0.f;
    __syncthreads();

    const char* ucrow = UcB + u * 512;
    int usw = (u & 31) << 4;
    int cb = half * 16;                                // chunk base for this half
    const char* hB = (const char*)h16;
    for (int t = 0; t < TT; ++t) {
        float acc0, acc1, acc2, acc3;
        if (half == 0) {
            const float* gx = Gx + ((size_t)t * BB + b) * 1024;
            acc0 = gx[u]; acc1 = gx[256 + u]; acc2 = gx[512 + u]; acc3 = gx[768 + u];
        } else {
            acc0 = acc1 = acc2 = acc3 = 0.f;
        }
        #pragma unroll
        for (int i = 0; i < 16; ++i) {
            u32x4 hv = *(const u32x4*)(hB + (cb + i) * 16);            // broadcast, free
            u32x4 cw = *(const u32x4*)(ucrow + (((cb + i) * 16) ^ usw)); // 1 b128, 2-way alias
            acc0 = fdot2u(hv.x, Ur[0][i].x, acc0); acc0 = fdot2u(hv.y, Ur[0][i].y, acc0);
            acc0 = fdot2u(hv.z, Ur[0][i].z, acc0); acc0 = fdot2u(hv.w, Ur[0][i].w, acc0);
            acc1 = fdot2u(hv.x, Ur[1][i].x, acc1); acc1 = fdot2u(hv.y, Ur[1][i].y, acc1);
            acc1 = fdot2u(hv.z, Ur[1][i].z, acc1); acc1 = fdot2u(hv.w, Ur[1][i].w, acc1);
            acc2 = fdot2u(hv.x, Ur[2][i].x, acc2); acc2 = fdot2u(hv.y, Ur[2][i].y, acc2);
            acc2 = fdot2u(hv.z, Ur[2][i].z, acc2); acc2 = fdot2u(hv.w, Ur[2][i].w, acc2);
            acc3 = fdot2u(hv.x, cw.x, acc3); acc3 = fdot2u(hv.y, cw.y, acc3);
            acc3 = fdot2u(hv.z, cw.z, acc3); acc3 = fdot2u(hv.w, cw.w, acc3);
        }
        if (half == 1) {
            part[0][u] = acc0; part[1][u] = acc1; part[2][u] = acc2; part[3][u] = acc3;
        }
        __syncthreads();
        if (half == 0) {
            float p0 = acc0 + part[0][u];
            float p1 = acc1 + part[1][u];
            float p2 = acc2 + part[2][u];
            float p3 = acc3 + part[3][u];
            float ig = sigmoid_f(p0), fg = sigmoid_f(p1), og = sigmoid_f(p2);
            float ch = tanh_f(p3);
            c = fg * c + ig * ch;
            float hn = og * tanh_f(c);
            unsigned short hbits = __builtin_bit_cast(unsigned short, (f16)hn);
            h16[u] = hbits;
            Hall[((size_t)b * TT + t) * HH + u] = hbits;   // row r = b*64 + t
        }
        __syncthreads();
    }
}

// ======== output GEMM passes: BM=256 (A in regs, 2 mfrag/wave), B staged via LDS ========
// block 512 = 8 waves; wave w owns rows r0 = mt*256 + w*32 (2 m-frags of 16).
// B col-tile (16 cols x 256 k = 8KB f16) double-buffered in LDS, XOR-swizzled
// (byte ^= (row&7)<<4, applied on ds_write AND ds_read - both-sides rule).
// One barrier per tile; stage-load issued before compute (latency hidden under MFMA).

// ---- pass 1: logits -> exp -> per-row sums (atomicAdd at end).
__global__ __launch_bounds__(512) void k_rowsum(const unsigned short* __restrict__ Hall,
                                                const unsigned short* __restrict__ WoT,
                                                const float* __restrict__ bo,
                                                float* __restrict__ rowsum) {
    __shared__ __align__(16) char Bs[2][8192];
    int mt = blockIdx.x & 15, nt = blockIdx.x >> 4;
    int tid = threadIdx.x, w = tid >> 6, lane = tid & 63;
    int lrow = lane & 15, q = lane >> 4;
    int r0 = mt * 256 + w * 32;
    int c0 = nt * SLICE;
    // A fragments: 2 m-frags x 8 kf, loaded once (64 VGPR)
    f16x8 a[2][8];
    #pragma unroll
    for (int m = 0; m < 2; ++m) {
        const unsigned short* ar = Hall + (size_t)(r0 + m * 16 + lrow) * HH + q * 8;
        #pragma unroll
        for (int kf = 0; kf < 8; ++kf) a[m][kf] = *(const f16x8*)(ar + kf * 32);
    }
    // staging coords: thread stages 16B: col-row cr (0..15), k-chunk kb (0..31)
    int cr = tid >> 5, kb = tid & 31;
    int wb = cr * 512 + ((kb * 16) ^ ((cr & 7) << 4));   // swizzled LDS byte
    const unsigned short* gsrc0 = WoT + (size_t)(c0 + cr) * HH + kb * 8;
    int rb = lrow * 512, sw = (lrow & 7) << 4;           // read-side swizzle
    {   // prologue: stage tile 0
        f16x8 v = *(const f16x8*)gsrc0;
        *(f16x8*)(Bs[0] + wb) = v;
    }
    __syncthreads();
    float rs[2][4] = {{0.f, 0.f, 0.f, 0.f}, {0.f, 0.f, 0.f, 0.f}};
    int buf = 0;
    for (int ct = 0; ct < NT_TILES; ++ct) {
        f16x8 stg;
        bool have = (ct + 1 < NT_TILES);
        if (have) stg = *(const f16x8*)(gsrc0 + (size_t)(ct + 1) * 16 * HH);
        f16x8 bfr[8];
        #pragma unroll
        for (int kf = 0; kf < 8; ++kf)
            bfr[kf] = *(const f16x8*)(Bs[buf] + rb + ((kf * 64 + q * 16) ^ sw));
        f32x4 acc0 = {0.f, 0.f, 0.f, 0.f}, acc1 = {0.f, 0.f, 0.f, 0.f};
        #pragma unroll
        for (int kf = 0; kf < 8; ++kf) {
            acc0 = __builtin_amdgcn_mfma_f32_16x16x32_f16(a[0][kf], bfr[kf], acc0, 0, 0, 0);
            acc1 = __builtin_amdgcn_mfma_f32_16x16x32_f16(a[1][kf], bfr[kf], acc1, 0, 0, 0);
        }
        float bv = bo[c0 + ct * 16 + lrow];
        #pragma unroll
        for (int j = 0; j < 4; ++j) {
            rs[0][j] += __expf(fminf(acc0[j] + bv, 60.f));
            rs[1][j] += __expf(fminf(acc1[j] + bv, 60.f));
        }
        if (have) *(f16x8*)(Bs[buf ^ 1] + wb) = stg;
        __syncthreads();
        buf ^= 1;
    }
    #pragma unroll
    for (int m = 0; m < 2; ++m) {
        #pragma unroll
        for (int j = 0; j < 4; ++j) {
            float v = rs[m][j];
            v += __shfl_xor(v, 1); v += __shfl_xor(v, 2);
            v += __shfl_xor(v, 4); v += __shfl_xor(v, 8);
            if (lrow == 0) atomicAdd(&rowsum[r0 + m * 16 + q * 4 + j], v);
        }
    }
}

// ---- pass 2: recompute logits, write exp(l)/rowsum directly to out (row r = b*64+t)
__global__ __launch_bounds__(512) void k_out(const unsigned short* __restrict__ Hall,
                                             const unsigned short* __restrict__ WoT,
                                             const float* __restrict__ bo,
                                             const float* __restrict__ rowsum,
                                             float* __restrict__ out) {
    __shared__ __align__(16) char Bs[2][8192];
    int mt = blockIdx.x & 15, nt = blockIdx.x >> 4;
    int tid = threadIdx.x, w = tid >> 6, lane = tid & 63;
    int lrow = lane & 15, q = lane >> 4;
    int r0 = mt * 256 + w * 32;
    int c0 = nt * SLICE;
    f16x8 a[2][8];
    #pragma unroll
    for (int m = 0; m < 2; ++m) {
        const unsigned short* ar = Hall + (size_t)(r0 + m * 16 + lrow) * HH + q * 8;
        #pragma unroll
        for (int kf = 0; kf < 8; ++kf) a[m][kf] = *(const f16x8*)(ar + kf * 32);
    }
    float ri[2][4];
    float* po[2][4];
    #pragma unroll
    for (int m = 0; m < 2; ++m) {
        f32x4 rv = *(const f32x4*)&rowsum[r0 + m * 16 + q * 4];
        #pragma unroll
        for (int j = 0; j < 4; ++j) {
            ri[m][j] = 1.f / rv[j];
            po[m][j] = out + (size_t)(r0 + m * 16 + q * 4 + j) * VV;
        }
    }
    int cr = tid >> 5, kb = tid & 31;
    int wb = cr * 512 + ((kb * 16) ^ ((cr & 7) << 4));
    const unsigned short* gsrc0 = WoT + (size_t)(c0 + cr) * HH + kb * 8;
    int rb = lrow * 512, sw = (lrow & 7) << 4;
    {
        f16x8 v = *(const f16x8*)gsrc0;
        *(f16x8*)(Bs[0] + wb) = v;
    }
    __syncthreads();
    int buf = 0;
    for (int ct = 0; ct < NT_TILES; ++ct) {
        f16x8 stg;
        bool have = (ct + 1 < NT_TILES);
        if (have) stg = *(const f16x8*)(gsrc0 + (size_t)(ct + 1) * 16 * HH);
        f16x8 bfr[8];
        #pragma unroll
        for (int kf = 0; kf < 8; ++kf)
            bfr[kf] = *(const f16x8*)(Bs[buf] + rb + ((kf * 64 + q * 16) ^ sw));
        f32x4 acc0 = {0.f, 0.f, 0.f, 0.f}, acc1 = {0.f, 0.f, 0.f, 0.f};
        #pragma unroll
        for (int kf = 0; kf < 8; ++kf) {
            acc0 = __builtin_amdgcn_mfma_f32_16x16x32_f16(a[0][kf], bfr[kf], acc0, 0, 0, 0);
            acc1 = __builtin_amdgcn_mfma_f32_16x16x32_f16(a[1][kf], bfr[kf], acc1, 0, 0, 0);
        }
        int col = c0 + ct * 16 + lrow;
        float bv = bo[col];
        #pragma unroll
        for (int j = 0; j < 4; ++j) {
            po[0][j][col] = __expf(fminf(acc0[j] + bv, 60.f)) * ri[0][j];
            po[1][j][col] = __expf(fminf(acc1[j] + bv, 60.f)) * ri[1][j];
        }
        if (have) *(f16x8*)(Bs[buf ^ 1] + wb) = stg;
        __syncthreads();
        buf ^= 1;
    }
}

extern "C" void kernel_launch(void* const* d_in, const int* in_sizes, int n_in,
                              void* d_out, int out_size, void* d_ws, size_t ws_size,
                              hipStream_t stream) {
    const int*   x    = (const int*)  d_in[0];
    const float* emb  = (const float*)d_in[1];
    const float* Wi   = (const float*)d_in[2];
    const float* Ui   = (const float*)d_in[3];
    const float* bi   = (const float*)d_in[4];
    const float* Wf   = (const float*)d_in[5];
    const float* Uf   = (const float*)d_in[6];
    const float* bfv  = (const float*)d_in[7];
    const float* Wog  = (const float*)d_in[8];
    const float* Uog  = (const float*)d_in[9];
    const float* bog  = (const float*)d_in[10];
    const float* Wc   = (const float*)d_in[11];
    const float* Uc   = (const float*)d_in[12];
    const float* bc   = (const float*)d_in[13];
    const float* Wo   = (const float*)d_in[14];
    const float* bo   = (const float*)d_in[15];
    float* out = (float*)d_out;
    char* ws = (char*)d_ws;

    // ws layout (~18.9 MB): Upk8 512KB | Hall 2MB | WoT 16,384,000B | rowsum 16KB
    f16*            Upk8   = (f16*)(ws);
    unsigned short* Hall   = (unsigned short*)(ws + (512u << 10));
    unsigned short* WoT    = (unsigned short*)(ws + (512u << 10) + (2u << 20));
    float*          rowsum = (float*)(ws + (512u << 10) + (2u << 20) + 16384000u);
    float*          Gx     = out;   // 16 MB scratch inside d_out; dead before k_out writes

    k_prep_u  <<<128, 256, 0, stream>>>(Ui, Uf, Uog, Uc, Upk8);
    k_prep_wot<<<500, 256, 0, stream>>>(Wo, WoT);
    k_zero    <<<16, 256, 0, stream>>>(rowsum, BB * TT);
    k_gx      <<<512, 256, 0, stream>>>(x, emb, Wi, Wf, Wog, Wc, bi, bfv, bog, bc, Gx);
    k_lstm    <<<64, 512, 0, stream>>>(Gx, Upk8, Hall);
    k_rowsum  <<<GRID_MN, 512, 0, stream>>>(Hall, WoT, bo, rowsum);
    k_out     <<<GRID_MN, 512, 0, stream>>>(Hall, WoT, bo, rowsum, out);
}

// Round 8
// 876.911 us; speedup vs baseline: 1.9742x; 1.0706x over previous
//
#include <hip/hip_runtime.h>
#include <hip/hip_fp16.h>

#define TT 64
#define BB 64
#define EE 128
#define HH 256
#define VV 32000
#define NT_TILES 25          // col-tiles per block (16 cols each)
#define SLICE 400            // NT_TILES*16
#define GRID_MN 1280         // 16 m-tiles x 80 n-slices = 5*256 (no tail)

typedef _Float16 f16;
typedef _Float16 f16x2 __attribute__((ext_vector_type(2)));
typedef _Float16 f16x8 __attribute__((ext_vector_type(8)));
typedef float f32x4 __attribute__((ext_vector_type(4)));
typedef unsigned u32x4 __attribute__((ext_vector_type(4)));

#if __has_builtin(__builtin_amdgcn_fdot2)
__device__ __forceinline__ float fdot2u(unsigned a, unsigned b, float c) {
    return __builtin_amdgcn_fdot2(__builtin_bit_cast(f16x2, a),
                                  __builtin_bit_cast(f16x2, b), c, false);
}
#else
__device__ __forceinline__ float fdot2u(unsigned a, unsigned b, float c) {
    f16x2 av = __builtin_bit_cast(f16x2, a), bv = __builtin_bit_cast(f16x2, b);
    return c + (float)av[0] * (float)bv[0] + (float)av[1] * (float)bv[1];
}
#endif

// async global->LDS, 16B per lane; LDS dest = wave-uniform base + lane*16 (linear)
__device__ __forceinline__ void gload_lds16(const void* g, void* l) {
    __builtin_amdgcn_global_load_lds(
        (const __attribute__((address_space(1))) unsigned*)g,
        (__attribute__((address_space(3))) unsigned*)l, 16, 0, 0);
}

__device__ __forceinline__ float sigmoid_f(float x) {
    return 1.f / (1.f + __expf(-x));
}
__device__ __forceinline__ float tanh_f(float x) {
    float e = __expf(2.f * x);
    return 1.f - 2.f / (e + 1.f);   // saturates correctly for |x| large
}

// ---- prep: pack U gates as f16 octets:
// Upk8[((g*32 + ko)*256 + u)] (f16x8 units) = U_g[8ko+j][u], j=0..7
__global__ void k_prep_u(const float* __restrict__ Ui, const float* __restrict__ Uf,
                         const float* __restrict__ Uog, const float* __restrict__ Uc,
                         f16* __restrict__ Upk8) {
    int idx = blockIdx.x * 256 + threadIdx.x;          // 4*32*256 = 32768
    if (idx >= 4 * 32 * 256) return;
    int u = idx & 255, ko = (idx >> 8) & 31, g = idx >> 13;
    const float* Ug = (g == 0) ? Ui : (g == 1) ? Uf : (g == 2) ? Uog : Uc;
    f16x8 v;
    #pragma unroll
    for (int j = 0; j < 8; ++j) v[j] = (f16)Ug[(8 * ko + j) * HH + u];
    ((f16x8*)Upk8)[idx] = v;
}

// ---- prep: WoT[v][k] = (f16) Wo[k][v]   (transpose for contiguous-k MFMA B frags)
__global__ void k_prep_wot(const float* __restrict__ Wo, unsigned short* __restrict__ WoT) {
    __shared__ unsigned short lds[64][258];            // pad -> conflict-free
    int v0 = blockIdx.x * 64;
    int tid = threadIdx.x;
    int vl = tid & 63, kq = tid >> 6;
    for (int it = 0; it < 64; ++it) {
        int k = it * 4 + kq;
        float w = Wo[(size_t)k * VV + v0 + vl];
        lds[vl][k] = __builtin_bit_cast(unsigned short, (f16)w);
    }
    __syncthreads();
    for (int r = 0; r < 64; ++r)
        WoT[(size_t)(v0 + r) * HH + tid] = lds[r][tid];
}

__global__ void k_zero(float* __restrict__ p, int n) {
    int i = blockIdx.x * 256 + threadIdx.x;
    if (i < n) p[i] = 0.f;
}

// ---- Gx[(t*64+b)*1024 + g*256 + u]; 8 rows per block for W reuse
__global__ __launch_bounds__(256) void k_gx(const int* __restrict__ x, const float* __restrict__ emb,
                     const float* __restrict__ Wi, const float* __restrict__ Wf,
                     const float* __restrict__ Wog, const float* __restrict__ Wc,
                     const float* __restrict__ bi, const float* __restrict__ bfv,
                     const float* __restrict__ bog, const float* __restrict__ bc,
                     float* __restrict__ Gx) {
    __shared__ float xs[8][EE];
    int base = blockIdx.x * 8;           // grid 512
    int tid = threadIdx.x;               // = hidden unit u
    for (int i = tid; i < 8 * EE; i += 256) {
        int r = i >> 7, k = i & 127;
        int bx = base + r, t = bx >> 6, b = bx & 63;
        int tok = (t == 0) ? 0 : x[b * TT + (t - 1)];
        xs[r][k] = emb[(size_t)tok * EE + k];
    }
    __syncthreads();
    float acc[4][8];
    float b0 = bi[tid], b1 = bfv[tid], b2 = bog[tid], b3 = bc[tid];
    #pragma unroll
    for (int r = 0; r < 8; ++r) {
        acc[0][r] = b0; acc[1][r] = b1; acc[2][r] = b2; acc[3][r] = b3;
    }
    for (int k = 0; k < EE; ++k) {
        float w0 = Wi[k * HH + tid], w1 = Wf[k * HH + tid];
        float w2 = Wog[k * HH + tid], w3 = Wc[k * HH + tid];
        #pragma unroll
        for (int r = 0; r < 8; ++r) {
            float xv = xs[r][k];
            acc[0][r] = fmaf(xv, w0, acc[0][r]);
            acc[1][r] = fmaf(xv, w1, acc[1][r]);
            acc[2][r] = fmaf(xv, w2, acc[2][r]);
            acc[3][r] = fmaf(xv, w3, acc[3][r]);
        }
    }
    #pragma unroll
    for (int r = 0; r < 8; ++r) {
        float* o = Gx + (size_t)(base + r) * 1024;
        o[tid] = acc[0][r]; o[256 + tid] = acc[1][r];
        o[512 + tid] = acc[2][r]; o[768 + tid] = acc[3][r];
    }
}

// ---- recurrence: one block per batch element, U fully CU-resident.
// 512 thr: u = tid&255, half = tid>>8 (K-split).
// LDS: U_c column-major-per-thread, XOR-swizzled chunks (one b128/inner-iter):
//   byte(u, c) = u*512 + ((c*16) ^ ((u&31)<<4)), c = 0..31 (16B chunk = 4 h-pairs)
// Regs: U_i/U_f/U_o K-half columns = u32x4 Ur[3][16] = 192 VGPRs, static-indexed.
__global__ __launch_bounds__(512) void k_lstm(const float* __restrict__ Gx,
                                              const f16* __restrict__ Upk8,
                                              unsigned short* __restrict__ Hall) {
    __shared__ __align__(16) char UcB[256 * 512];      // 128 KB
    __shared__ float part[4][256];                     // half=1 partials
    __shared__ __align__(16) unsigned short h16[HH];   // h state, f16
    int b = blockIdx.x, tid = threadIdx.x;
    int u = tid & 255, half = tid >> 8;
    const u32x4* U4 = (const u32x4*)Upk8;

    // fill U_c: octet ko of column uu == chunk ko of column uu (pure repack)
    for (int idx = tid; idx < 32 * 256; idx += 512) {
        int ko = idx >> 8, uu = idx & 255;
        u32x4 q = U4[(96 + ko) * 256 + uu];
        *(u32x4*)(UcB + uu * 512 + ((ko * 16) ^ ((uu & 31) << 4))) = q;
    }
    if (tid < HH / 2) ((unsigned*)h16)[tid] = 0u;

    // register-resident U for gates i,f,o: this thread's (u, K-half) columns
    u32x4 Ur[3][16];
    #pragma unroll
    for (int g = 0; g < 3; ++g) {
        #pragma unroll
        for (int i = 0; i < 16; ++i)
            Ur[g][i] = U4[(size_t)((g * 32 + half * 16 + i) * 256 + u)];
    }
    float c = 0.f;
    __syncthreads();

    const char* ucrow = UcB + u * 512;
    int usw = (u & 31) << 4;
    int cb = half * 16;                                // chunk base for this half
    const char* hB = (const char*)h16;
    for (int t = 0; t < TT; ++t) {
        float acc0, acc1, acc2, acc3;
        if (half == 0) {
            const float* gx = Gx + ((size_t)t * BB + b) * 1024;
            acc0 = gx[u]; acc1 = gx[256 + u]; acc2 = gx[512 + u]; acc3 = gx[768 + u];
        } else {
            acc0 = acc1 = acc2 = acc3 = 0.f;
        }
        #pragma unroll
        for (int i = 0; i < 16; ++i) {
            u32x4 hv = *(const u32x4*)(hB + (cb + i) * 16);            // broadcast, free
            u32x4 cw = *(const u32x4*)(ucrow + (((cb + i) * 16) ^ usw)); // 1 b128, 2-way alias
            acc0 = fdot2u(hv.x, Ur[0][i].x, acc0); acc0 = fdot2u(hv.y, Ur[0][i].y, acc0);
            acc0 = fdot2u(hv.z, Ur[0][i].z, acc0); acc0 = fdot2u(hv.w, Ur[0][i].w, acc0);
            acc1 = fdot2u(hv.x, Ur[1][i].x, acc1); acc1 = fdot2u(hv.y, Ur[1][i].y, acc1);
            acc1 = fdot2u(hv.z, Ur[1][i].z, acc1); acc1 = fdot2u(hv.w, Ur[1][i].w, acc1);
            acc2 = fdot2u(hv.x, Ur[2][i].x, acc2); acc2 = fdot2u(hv.y, Ur[2][i].y, acc2);
            acc2 = fdot2u(hv.z, Ur[2][i].z, acc2); acc2 = fdot2u(hv.w, Ur[2][i].w, acc2);
            acc3 = fdot2u(hv.x, cw.x, acc3); acc3 = fdot2u(hv.y, cw.y, acc3);
            acc3 = fdot2u(hv.z, cw.z, acc3); acc3 = fdot2u(hv.w, cw.w, acc3);
        }
        if (half == 1) {
            part[0][u] = acc0; part[1][u] = acc1; part[2][u] = acc2; part[3][u] = acc3;
        }
        __syncthreads();
        if (half == 0) {
            float p0 = acc0 + part[0][u];
            float p1 = acc1 + part[1][u];
            float p2 = acc2 + part[2][u];
            float p3 = acc3 + part[3][u];
            float ig = sigmoid_f(p0), fg = sigmoid_f(p1), og = sigmoid_f(p2);
            float ch = tanh_f(p3);
            c = fg * c + ig * ch;
            float hn = og * tanh_f(c);
            unsigned short hbits = __builtin_bit_cast(unsigned short, (f16)hn);
            h16[u] = hbits;
            Hall[((size_t)b * TT + t) * HH + u] = hbits;   // row r = b*64 + t
        }
        __syncthreads();
    }
}

// ======== output GEMM passes: BM=256 (A in regs, 2 mfrag/wave), B via global_load_lds ========
// block 512 = 8 waves; wave w owns rows r0 = mt*256 + w*32 (2 m-frags of 16).
// B col-tile (16 cols x 256 k = 8KB f16) double-buffered in LDS. gload_lds writes
// LINEARLY (slot s of col cr at byte cr*512 + s*16); the SOURCE is pre-swizzled:
// slot s holds chunk kb = (s&24)|((s&7)^(cr&7)). Read-side XOR ((4kf+q)^lr7)
// then recovers chunk 4kf+q — same involution both sides (rule #21).

// ---- pass 1: logits -> exp -> per-row sums (atomicAdd at end).
__global__ __launch_bounds__(512) void k_rowsum(const unsigned short* __restrict__ Hall,
                                                const unsigned short* __restrict__ WoT,
                                                const float* __restrict__ bo,
                                                float* __restrict__ rowsum) {
    __shared__ __align__(16) char Bs[2][8192];
    int mt = blockIdx.x & 15, nt = blockIdx.x >> 4;
    int tid = threadIdx.x, w = tid >> 6, lane = tid & 63;
    int lrow = lane & 15, q = lane >> 4;
    int r0 = mt * 256 + w * 32;
    int c0 = nt * SLICE;
    // A fragments: 2 m-frags x 8 kf, loaded once (64 VGPR)
    f16x8 a[2][8];
    #pragma unroll
    for (int m = 0; m < 2; ++m) {
        const unsigned short* ar = Hall + (size_t)(r0 + m * 16 + lrow) * HH + q * 8;
        #pragma unroll
        for (int kf = 0; kf < 8; ++kf) a[m][kf] = *(const f16x8*)(ar + kf * 32);
    }
    // staging coords: thread covers (col cr, linear slot s); source chunk pre-swizzled
    int cr = tid >> 5, s = tid & 31;
    int kb = (s & 24) | ((s & 7) ^ (cr & 7));
    const unsigned short* gsrc0 = WoT + (size_t)(c0 + cr) * HH + kb * 8;
    char* ldst0 = Bs[0] + (tid >> 6) * 1024;             // wave-uniform base (+lane*16 by HW)
    int rb = lrow * 512, sw = (lrow & 7) << 4;           // read-side swizzle
    gload_lds16(gsrc0, ldst0);                           // prologue: stage tile 0
    __syncthreads();
    float rs[2][4] = {{0.f, 0.f, 0.f, 0.f}, {0.f, 0.f, 0.f, 0.f}};
    int buf = 0;
    for (int ct = 0; ct < NT_TILES; ++ct) {
        if (ct + 1 < NT_TILES)
            gload_lds16(gsrc0 + (size_t)(ct + 1) * 16 * HH, ldst0 + (buf ^ 1) * 8192);
        f16x8 bfr[8];
        #pragma unroll
        for (int kf = 0; kf < 8; ++kf)
            bfr[kf] = *(const f16x8*)(Bs[buf] + rb + ((kf * 64 + q * 16) ^ sw));
        f32x4 acc0 = {0.f, 0.f, 0.f, 0.f}, acc1 = {0.f, 0.f, 0.f, 0.f};
        #pragma unroll
        for (int kf = 0; kf < 8; ++kf) {
            acc0 = __builtin_amdgcn_mfma_f32_16x16x32_f16(a[0][kf], bfr[kf], acc0, 0, 0, 0);
            acc1 = __builtin_amdgcn_mfma_f32_16x16x32_f16(a[1][kf], bfr[kf], acc1, 0, 0, 0);
        }
        float bv = bo[c0 + ct * 16 + lrow];
        #pragma unroll
        for (int j = 0; j < 4; ++j) {
            rs[0][j] += __expf(fminf(acc0[j] + bv, 60.f));
            rs[1][j] += __expf(fminf(acc1[j] + bv, 60.f));
        }
        __syncthreads();                                 // staged tile complete (vmcnt drained)
        buf ^= 1;
    }
    #pragma unroll
    for (int m = 0; m < 2; ++m) {
        #pragma unroll
        for (int j = 0; j < 4; ++j) {
            float v = rs[m][j];
            v += __shfl_xor(v, 1); v += __shfl_xor(v, 2);
            v += __shfl_xor(v, 4); v += __shfl_xor(v, 8);
            if (lrow == 0) atomicAdd(&rowsum[r0 + m * 16 + q * 4 + j], v);
        }
    }
}

// ---- pass 2: recompute logits, write exp(l)/rowsum directly to out (row r = b*64+t)
__global__ __launch_bounds__(512) void k_out(const unsigned short* __restrict__ Hall,
                                             const unsigned short* __restrict__ WoT,
                                             const float* __restrict__ bo,
                                             const float* __restrict__ rowsum,
                                             float* __restrict__ out) {
    __shared__ __align__(16) char Bs[2][8192];
    int mt = blockIdx.x & 15, nt = blockIdx.x >> 4;
    int tid = threadIdx.x, w = tid >> 6, lane = tid & 63;
    int lrow = lane & 15, q = lane >> 4;
    int r0 = mt * 256 + w * 32;
    int c0 = nt * SLICE;
    f16x8 a[2][8];
    #pragma unroll
    for (int m = 0; m < 2; ++m) {
        const unsigned short* ar = Hall + (size_t)(r0 + m * 16 + lrow) * HH + q * 8;
        #pragma unroll
        for (int kf = 0; kf < 8; ++kf) a[m][kf] = *(const f16x8*)(ar + kf * 32);
    }
    float ri[2][4];
    float* po[2][4];
    #pragma unroll
    for (int m = 0; m < 2; ++m) {
        f32x4 rv = *(const f32x4*)&rowsum[r0 + m * 16 + q * 4];
        #pragma unroll
        for (int j = 0; j < 4; ++j) {
            ri[m][j] = 1.f / rv[j];
            po[m][j] = out + (size_t)(r0 + m * 16 + q * 4 + j) * VV;
        }
    }
    int cr = tid >> 5, s = tid & 31;
    int kb = (s & 24) | ((s & 7) ^ (cr & 7));
    const unsigned short* gsrc0 = WoT + (size_t)(c0 + cr) * HH + kb * 8;
    char* ldst0 = Bs[0] + (tid >> 6) * 1024;
    int rb = lrow * 512, sw = (lrow & 7) << 4;
    gload_lds16(gsrc0, ldst0);
    __syncthreads();
    int buf = 0;
    for (int ct = 0; ct < NT_TILES; ++ct) {
        if (ct + 1 < NT_TILES)
            gload_lds16(gsrc0 + (size_t)(ct + 1) * 16 * HH, ldst0 + (buf ^ 1) * 8192);
        f16x8 bfr[8];
        #pragma unroll
        for (int kf = 0; kf < 8; ++kf)
            bfr[kf] = *(const f16x8*)(Bs[buf] + rb + ((kf * 64 + q * 16) ^ sw));
        f32x4 acc0 = {0.f, 0.f, 0.f, 0.f}, acc1 = {0.f, 0.f, 0.f, 0.f};
        #pragma unroll
        for (int kf = 0; kf < 8; ++kf) {
            acc0 = __builtin_amdgcn_mfma_f32_16x16x32_f16(a[0][kf], bfr[kf], acc0, 0, 0, 0);
            acc1 = __builtin_amdgcn_mfma_f32_16x16x32_f16(a[1][kf], bfr[kf], acc1, 0, 0, 0);
        }
        int col = c0 + ct * 16 + lrow;
        float bv = bo[col];
        #pragma unroll
        for (int j = 0; j < 4; ++j) {
            __builtin_nontemporal_store(__expf(fminf(acc0[j] + bv, 60.f)) * ri[0][j], &po[0][j][col]);
            __builtin_nontemporal_store(__expf(fminf(acc1[j] + bv, 60.f)) * ri[1][j], &po[1][j][col]);
        }
        __syncthreads();
        buf ^= 1;
    }
}

extern "C" void kernel_launch(void* const* d_in, const int* in_sizes, int n_in,
                              void* d_out, int out_size, void* d_ws, size_t ws_size,
                              hipStream_t stream) {
    const int*   x    = (const int*)  d_in[0];
    const float* emb  = (const float*)d_in[1];
    const float* Wi   = (const float*)d_in[2];
    const float* Ui   = (const float*)d_in[3];
    const float* bi   = (const float*)d_in[4];
    const float* Wf   = (const float*)d_in[5];
    const float* Uf   = (const float*)d_in[6];
    const float* bfv  = (const float*)d_in[7];
    const float* Wog  = (const float*)d_in[8];
    const float* Uog  = (const float*)d_in[9];
    const float* bog  = (const float*)d_in[10];
    const float* Wc   = (const float*)d_in[11];
    const float* Uc   = (const float*)d_in[12];
    const float* bc   = (const float*)d_in[13];
    const float* Wo   = (const float*)d_in[14];
    const float* bo   = (const float*)d_in[15];
    float* out = (float*)d_out;
    char* ws = (char*)d_ws;

    // ws layout (~18.9 MB): Upk8 512KB | Hall 2MB | WoT 16,384,000B | rowsum 16KB
    f16*            Upk8   = (f16*)(ws);
    unsigned short* Hall   = (unsigned short*)(ws + (512u << 10));
    unsigned short* WoT    = (unsigned short*)(ws + (512u << 10) + (2u << 20));
    float*          rowsum = (float*)(ws + (512u << 10) + (2u << 20) + 16384000u);
    float*          Gx     = out;   // 16 MB scratch inside d_out; dead before k_out writes

    k_prep_u  <<<128, 256, 0, stream>>>(Ui, Uf, Uog, Uc, Upk8);
    k_prep_wot<<<500, 256, 0, stream>>>(Wo, WoT);
    k_zero    <<<16, 256, 0, stream>>>(rowsum, BB * TT);
    k_gx      <<<512, 256, 0, stream>>>(x, emb, Wi, Wf, Wog, Wc, bi, bfv, bog, bc, Gx);
    k_lstm    <<<64, 512, 0, stream>>>(Gx, Upk8, Hall);
    k_rowsum  <<<GRID_MN, 512, 0, stream>>>(Hall, WoT, bo, rowsum);
    k_out     <<<GRID_MN, 512, 0, stream>>>(Hall, WoT, bo, rowsum, out);
}